// Round 2
// baseline (1183.793 us; speedup 1.0000x reference)
//
#include <hip/hip_runtime.h>

typedef __bf16 bf16_t;
typedef __attribute__((ext_vector_type(8))) __bf16 bf16x8;
typedef __attribute__((ext_vector_type(4))) __bf16 bf16x4;
typedef __attribute__((ext_vector_type(4))) float f32x4;

// ---------------------------------------------------------------- helpers
__device__ __forceinline__ void async_copy16(const bf16_t* g, bf16_t* l) {
    __builtin_amdgcn_global_load_lds(
        (const __attribute__((address_space(1))) void*)g,
        (__attribute__((address_space(3))) void*)l, 16, 0, 0);
}

// ---------------------------------------------------------------- W [K,N] f32 -> Wt [N,K] bf16
__global__ __launch_bounds__(256) void transpose_to_bf16(const float* __restrict__ in,
                                                         bf16_t* __restrict__ out,
                                                         int K, int N) {
    __shared__ float tile[32][33];
    int t = threadIdx.x;
    int tx = t & 31, ty = t >> 5;              // 32 x 8
    int n0 = blockIdx.x * 32, k0 = blockIdx.y * 32;
#pragma unroll
    for (int i = 0; i < 4; i++) {
        int k = k0 + ty + i * 8;
        tile[ty + i * 8][tx] = in[(size_t)k * N + n0 + tx];
    }
    __syncthreads();
#pragma unroll
    for (int i = 0; i < 4; i++) {
        int n = n0 + ty + i * 8;
        out[(size_t)n * K + k0 + tx] = (bf16_t)tile[tx][ty + i * 8];
    }
}

// ---------------------------------------------------------------- GEMM: C[M,N] = A[M,K] @ Bt[N,K]^T (+bias)
// 128x128 tile, 4 waves, 16x16x32 bf16 MFMA, global_load_lds width-16 staging.
__global__ __launch_bounds__(256) void gemm_bt(const bf16_t* __restrict__ A,
                                               const bf16_t* __restrict__ Bt,
                                               const float* __restrict__ bias,
                                               float* __restrict__ outF,
                                               bf16_t* __restrict__ outB,
                                               int M, int N, int K) {
    __shared__ bf16_t As[128 * 32];
    __shared__ bf16_t Bs[128 * 32];
    const int t = threadIdx.x;
    const int w = t >> 6, lane = t & 63;
    const int quad = lane >> 4, l16 = lane & 15;
    const int bm = blockIdx.x * 128, bn = blockIdx.y * 128;
    const int wm = (w >> 1) * 64, wn = (w & 1) * 64;

    const f32x4 zero = {0.f, 0.f, 0.f, 0.f};
    f32x4 acc[4][4];
#pragma unroll
    for (int i = 0; i < 4; i++)
#pragma unroll
        for (int j = 0; j < 4; j++) acc[i][j] = zero;

    const int srow = t >> 2;          // 0..63
    const int scol = (t & 3) * 8;     // element offset within 32
    const bf16_t* ga = A + (size_t)(bm + srow) * K + scol;
    const bf16_t* gb = Bt + (size_t)(bn + srow) * K + scol;
    bf16_t* la = As + w * 512;        // wave-uniform LDS base
    bf16_t* lb = Bs + w * 512;

    for (int k0 = 0; k0 < K; k0 += 32) {
        async_copy16(ga + k0, la);
        async_copy16(ga + k0 + (size_t)64 * K, la + 2048);
        async_copy16(gb + k0, lb);
        async_copy16(gb + k0 + (size_t)64 * K, lb + 2048);
        __syncthreads();
        bf16x8 af[4], bf[4];
#pragma unroll
        for (int i = 0; i < 4; i++)
            af[i] = *(const bf16x8*)(As + (wm + i * 16 + l16) * 32 + quad * 8);
#pragma unroll
        for (int j = 0; j < 4; j++)
            bf[j] = *(const bf16x8*)(Bs + (wn + j * 16 + l16) * 32 + quad * 8);
#pragma unroll
        for (int i = 0; i < 4; i++)
#pragma unroll
            for (int j = 0; j < 4; j++)
                acc[i][j] = __builtin_amdgcn_mfma_f32_16x16x32_bf16(af[i], bf[j], acc[i][j], 0, 0, 0);
        __syncthreads();
    }

    // epilogue: C/D layout col=lane&15, row=quad*4+reg
#pragma unroll
    for (int i = 0; i < 4; i++) {
        int r0 = bm + wm + i * 16 + quad * 4;
#pragma unroll
        for (int j = 0; j < 4; j++) {
            int c = bn + wn + j * 16 + l16;
            float bsv = bias ? bias[c] : 0.f;
#pragma unroll
            for (int r = 0; r < 4; r++) {
                float v = acc[i][j][r] + bsv;
                size_t idx = (size_t)(r0 + r) * N + c;
                if (outF) outF[idx] = v;
                if (outB) outB[idx] = (bf16_t)v;
            }
        }
    }
}

// ---------------------------------------------------------------- GEMM with f32 A (fused convert in staging)
// Same tile structure; A-tile loaded f32 via registers, converted to bf16 in LDS.
__global__ __launch_bounds__(256) void gemm_f32a(const float* __restrict__ A,
                                                 const bf16_t* __restrict__ Bt,
                                                 const float* __restrict__ bias,
                                                 bf16_t* __restrict__ outB,
                                                 int M, int N, int K) {
    __shared__ bf16_t As[128 * 32];
    __shared__ bf16_t Bs[128 * 32];
    const int t = threadIdx.x;
    const int w = t >> 6, lane = t & 63;
    const int quad = lane >> 4, l16 = lane & 15;
    const int bm = blockIdx.x * 128, bn = blockIdx.y * 128;
    const int wm = (w >> 1) * 64, wn = (w & 1) * 64;

    const f32x4 zero = {0.f, 0.f, 0.f, 0.f};
    f32x4 acc[4][4];
#pragma unroll
    for (int i = 0; i < 4; i++)
#pragma unroll
        for (int j = 0; j < 4; j++) acc[i][j] = zero;

    const int arow = t >> 1, acol = (t & 1) * 16;   // 128 rows x 32 cols, 16 f32 per thread pair-half
    const float* ga = A + (size_t)(bm + arow) * K + acol;
    const int srow = t >> 2, scol = (t & 3) * 8;
    const bf16_t* gb = Bt + (size_t)(bn + srow) * K + scol;
    bf16_t* lb = Bs + w * 512;

    for (int k0 = 0; k0 < K; k0 += 32) {
        async_copy16(gb + k0, lb);
        async_copy16(gb + k0 + (size_t)64 * K, lb + 2048);
        float4 v0 = *(const float4*)(ga + k0);
        float4 v1 = *(const float4*)(ga + k0 + 4);
        float4 v2 = *(const float4*)(ga + k0 + 8);
        float4 v3 = *(const float4*)(ga + k0 + 12);
        bf16x8 o0, o1;
        o0[0] = (__bf16)v0.x; o0[1] = (__bf16)v0.y; o0[2] = (__bf16)v0.z; o0[3] = (__bf16)v0.w;
        o0[4] = (__bf16)v1.x; o0[5] = (__bf16)v1.y; o0[6] = (__bf16)v1.z; o0[7] = (__bf16)v1.w;
        o1[0] = (__bf16)v2.x; o1[1] = (__bf16)v2.y; o1[2] = (__bf16)v2.z; o1[3] = (__bf16)v2.w;
        o1[4] = (__bf16)v3.x; o1[5] = (__bf16)v3.y; o1[6] = (__bf16)v3.z; o1[7] = (__bf16)v3.w;
        *(bf16x8*)(As + arow * 32 + acol) = o0;
        *(bf16x8*)(As + arow * 32 + acol + 8) = o1;
        __syncthreads();
        bf16x8 af[4], bf[4];
#pragma unroll
        for (int i = 0; i < 4; i++)
            af[i] = *(const bf16x8*)(As + (wm + i * 16 + l16) * 32 + quad * 8);
#pragma unroll
        for (int j = 0; j < 4; j++)
            bf[j] = *(const bf16x8*)(Bs + (wn + j * 16 + l16) * 32 + quad * 8);
#pragma unroll
        for (int i = 0; i < 4; i++)
#pragma unroll
            for (int j = 0; j < 4; j++)
                acc[i][j] = __builtin_amdgcn_mfma_f32_16x16x32_bf16(af[i], bf[j], acc[i][j], 0, 0, 0);
        __syncthreads();
    }

#pragma unroll
    for (int i = 0; i < 4; i++) {
        int r0 = bm + wm + i * 16 + quad * 4;
#pragma unroll
        for (int j = 0; j < 4; j++) {
            int c = bn + wn + j * 16 + l16;
            float bsv = bias ? bias[c] : 0.f;
#pragma unroll
            for (int r = 0; r < 4; r++)
                outB[(size_t)(r0 + r) * N + c] = (bf16_t)(acc[i][j][r] + bsv);
        }
    }
}

// ---------------------------------------------------------------- fused attention per (b, head)
// Q [B*LQ,1024] bf16, K [B*LK,1024], V [B*LK,1024]; head h uses cols h*256..+256 (d=256).
// S = QK^T/16 masked -> softmax (masked==0 exactly, all-masked row -> 0) -> O = P V.
template <int LQ, int LK>
__global__ __launch_bounds__(256) void attn_kernel(const bf16_t* __restrict__ Q,
                                                   const bf16_t* __restrict__ Kb,
                                                   const bf16_t* __restrict__ V,
                                                   const int* __restrict__ qmask,
                                                   const int* __restrict__ kmask,
                                                   bf16_t* __restrict__ O) {
    constexpr int VSTR = LK + 8;      // 16B-aligned rows, 2-way (free) bank pattern
    constexpr int NQT = LQ / 16, NKT = LK / 16, NKB = LK / 32;
    __shared__ bf16_t Vt[256 * VSTR];         // V^T per head: [e][k]
    __shared__ bf16_t Pb[4 * 16 * LK];        // per-wave P strip [16][LK]

    const int t = threadIdx.x;
    const int w = t >> 6, lane = t & 63;
    const int quad = lane >> 4, l16 = lane & 15;
    const int b = blockIdx.x >> 2;
    const int h = blockIdx.x & 3;
    const int hoff = h * 256;

    for (int idx = t; idx < LK * 32; idx += 256) {
        int k = idx % LK;
        int e0 = (idx / LK) * 8;
        bf16x8 v = *(const bf16x8*)(V + (size_t)(b * LK + k) * 1024 + hoff + e0);
#pragma unroll
        for (int j = 0; j < 8; j++) Vt[(e0 + j) * VSTR + k] = v[j];
    }
    __syncthreads();

    bf16_t* P = Pb + w * (16 * LK);

    for (int qt = w; qt < NQT; qt += 4) {
        const int qrow = b * LQ + qt * 16;
        bf16x8 qf[8];
#pragma unroll
        for (int kb = 0; kb < 8; kb++)
            qf[kb] = *(const bf16x8*)(Q + (size_t)(qrow + l16) * 1024 + hoff + kb * 32 + quad * 8);

        f32x4 s[NKT];
        const f32x4 zero = {0.f, 0.f, 0.f, 0.f};
#pragma unroll
        for (int nt = 0; nt < NKT; nt++) {
            f32x4 a = zero;
#pragma unroll
            for (int kb = 0; kb < 8; kb++) {
                bf16x8 kf = *(const bf16x8*)(Kb + (size_t)(b * LK + nt * 16 + l16) * 1024 + hoff + kb * 32 + quad * 8);
                a = __builtin_amdgcn_mfma_f32_16x16x32_bf16(qf[kb], kf, a, 0, 0, 0);
            }
            s[nt] = a;
        }

        int km[NKT];
#pragma unroll
        for (int nt = 0; nt < NKT; nt++) km[nt] = kmask[b * LK + nt * 16 + l16];
        int qmv[4];
#pragma unroll
        for (int r = 0; r < 4; r++) qmv[r] = qmask[b * LQ + qt * 16 + quad * 4 + r];

        float rmax[4], rsum[4];
#pragma unroll
        for (int r = 0; r < 4; r++) rmax[r] = -3.0e38f;
#pragma unroll
        for (int nt = 0; nt < NKT; nt++)
#pragma unroll
            for (int r = 0; r < 4; r++) {
                float v = s[nt][r] * 0.0625f;   // 1/sqrt(256)
                bool ok = (qmv[r] != 0) && (km[nt] != 0);
                s[nt][r] = ok ? v : -3.0e38f;
                rmax[r] = fmaxf(rmax[r], s[nt][r]);
            }
#pragma unroll
        for (int r = 0; r < 4; r++)
            for (int off = 1; off < 16; off <<= 1)
                rmax[r] = fmaxf(rmax[r], __shfl_xor(rmax[r], off, 16));
#pragma unroll
        for (int r = 0; r < 4; r++) rsum[r] = 0.f;
#pragma unroll
        for (int nt = 0; nt < NKT; nt++)
#pragma unroll
            for (int r = 0; r < 4; r++) {
                float p = (s[nt][r] > -1.0e38f) ? __expf(s[nt][r] - rmax[r]) : 0.f;
                s[nt][r] = p;
                rsum[r] += p;
            }
#pragma unroll
        for (int r = 0; r < 4; r++)
            for (int off = 1; off < 16; off <<= 1)
                rsum[r] += __shfl_xor(rsum[r], off, 16);
#pragma unroll
        for (int r = 0; r < 4; r++) rsum[r] = (rsum[r] > 0.f) ? 1.f / rsum[r] : 0.f;

#pragma unroll
        for (int nt = 0; nt < NKT; nt++)
#pragma unroll
            for (int r = 0; r < 4; r++)
                P[(quad * 4 + r) * LK + nt * 16 + l16] = (bf16_t)(s[nt][r] * rsum[r]);
        asm volatile("s_waitcnt lgkmcnt(0)" ::: "memory");

        bf16x8 pf[NKB];
#pragma unroll
        for (int kb = 0; kb < NKB; kb++)
            pf[kb] = *(const bf16x8*)(P + l16 * LK + kb * 32 + quad * 8);

#pragma unroll
        for (int et = 0; et < 16; et++) {
            f32x4 o = zero;
#pragma unroll
            for (int kb = 0; kb < NKB; kb++) {
                bf16x8 vf = *(const bf16x8*)(Vt + (et * 16 + l16) * VSTR + kb * 32 + quad * 8);
                o = __builtin_amdgcn_mfma_f32_16x16x32_bf16(pf[kb], vf, o, 0, 0, 0);
            }
#pragma unroll
            for (int r = 0; r < 4; r++)
                O[(size_t)(qrow + quad * 4 + r) * 1024 + hoff + et * 16 + l16] = (bf16_t)o[r];
        }
    }
}

// ---------------------------------------------------------------- LayerNorm over D=1024, eps=1e-3
__global__ __launch_bounds__(256) void ln_kernel(const float* __restrict__ in,
                                                 const float* __restrict__ g,
                                                 const float* __restrict__ be,
                                                 float* __restrict__ outF,
                                                 bf16_t* __restrict__ outB) {
    __shared__ float red[8];
    const int row = blockIdx.x, t = threadIdx.x;
    const float* x = in + (size_t)row * 1024;
    float4 v = *(const float4*)(x + t * 4);
    float s = v.x + v.y + v.z + v.w;
    float ss = v.x * v.x + v.y * v.y + v.z * v.z + v.w * v.w;
    for (int off = 1; off < 64; off <<= 1) {
        s += __shfl_xor(s, off);
        ss += __shfl_xor(ss, off);
    }
    int w = t >> 6, lane = t & 63;
    if (lane == 0) { red[w * 2] = s; red[w * 2 + 1] = ss; }
    __syncthreads();
    if (t == 0) {
        float a = 0.f, b2 = 0.f;
        for (int i = 0; i < 4; i++) { a += red[i * 2]; b2 += red[i * 2 + 1]; }
        red[0] = a; red[1] = b2;
    }
    __syncthreads();
    float mean = red[0] * (1.f / 1024.f);
    float var = red[1] * (1.f / 1024.f) - mean * mean;
    float rstd = rsqrtf(var + 1e-3f);
    float4 gv = *(const float4*)(g + t * 4);
    float4 bv = *(const float4*)(be + t * 4);
    float y0 = (v.x - mean) * rstd * gv.x + bv.x;
    float y1 = (v.y - mean) * rstd * gv.y + bv.y;
    float y2 = (v.z - mean) * rstd * gv.z + bv.z;
    float y3 = (v.w - mean) * rstd * gv.w + bv.w;
    if (outF) {
        float4 o = {y0, y1, y2, y3};
        *(float4*)(outF + (size_t)row * 1024 + t * 4) = o;
    }
    if (outB) {
        bf16x4 o;
        o[0] = (__bf16)y0; o[1] = (__bf16)y1; o[2] = (__bf16)y2; o[3] = (__bf16)y3;
        *(bf16x4*)(outB + (size_t)row * 1024 + t * 4) = o;
    }
}

// ---------------------------------------------------------------- host orchestration
// Workspace plan (total ~148 MB; Round-0's 360 MB likely overflowed ws_size -> GPU fault):
//   S0..S5 : 6 x 25,165,824 B (bf16 [12288,1024] each)
//   Wb     : 4,194,304 B (one transposed-weight buffer, reused 18x; same-stream serializes)
//   f32 LN buffers overlay dead slot pairs: f32_01 = S0..S1, f32_23 = S2..S3.
extern "C" void kernel_launch(void* const* d_in, const int* in_sizes, int n_in,
                              void* d_out, int out_size, void* d_ws, size_t ws_size,
                              hipStream_t stream) {
    (void)in_sizes; (void)n_in; (void)out_size; (void)ws_size;
    const float* tE = (const float*)d_in[0];   // [128,96,1024]
    const float* iE = (const float*)d_in[1];   // [128,64,2048]
    const int* tMask = (const int*)d_in[2];    // [128,96]
    const int* iMask = (const int*)d_in[3];    // [128,64]

    char* ws = (char*)d_ws;
    const size_t SLOT = (size_t)12288 * 1024 * 2;
    bf16_t* S[6];
    for (int i = 0; i < 6; i++) S[i] = (bf16_t*)(ws + i * SLOT);
    bf16_t* Wb = (bf16_t*)(ws + 6 * SLOT);
    float* f32_01 = (float*)S[0];   // 48 MB span (S0,S1)
    float* f32_23 = (float*)S[2];   // 48 MB span (S2,S3)

    auto TW = [&](int idx) {
        int K = (idx == 6 || idx == 14) ? 2048 : 1024;
        transpose_to_bf16<<<dim3(32, K / 32), 256, 0, stream>>>((const float*)d_in[idx], Wb, K, 1024);
    };
    auto gemm = [&](const bf16_t* A, const float* bias, float* oF, bf16_t* oB, int M, int K) {
        gemm_bt<<<dim3(M / 128, 8), 256, 0, stream>>>(A, Wb, bias, oF, oB, M, 1024, K);
    };
    auto gemmF = [&](const float* A, const float* bias, bf16_t* oB, int M, int K) {
        gemm_f32a<<<dim3(M / 128, 8), 256, 0, stream>>>(A, Wb, bias, oB, M, 1024, K);
    };

    // projections (f32 A path; embeddings never materialized in bf16)
    TW(4);  gemmF(tE, (const float*)d_in[5], S[0], 12288, 1024);        // tP   -> S0
    TW(6);  gemmF(iE, (const float*)d_in[7], S[1], 8192, 2048);         // iP   -> S1
    // text cross-attn (query=image_proj, key=text_proj, value=RAW text)
    TW(8);  gemm(S[1], nullptr, nullptr, S[2], 8192, 1024);             // taQ  -> S2
    TW(9);  gemm(S[0], nullptr, nullptr, S[3], 12288, 1024);            // taK  -> S3
    TW(10); gemmF(tE, nullptr, S[4], 12288, 1024);                      // taV  -> S4
    attn_kernel<64, 96><<<512, 256, 0, stream>>>(S[2], S[3], S[4], iMask, tMask, S[5]);  // taO -> S5
    // image cross-attn
    TW(12); gemm(S[0], nullptr, nullptr, S[2], 12288, 1024);            // iaQ  -> S2 (S0 dead after)
    TW(13); gemm(S[1], nullptr, nullptr, S[3], 8192, 1024);             // iaK  -> S3 (S1 dead after)
    TW(14); gemmF(iE, nullptr, S[4], 8192, 2048);                       // iaV  -> S4
    attn_kernel<96, 64><<<512, 256, 0, stream>>>(S[2], S[3], S[4], tMask, iMask, S[0]);  // iaO -> S0
    // out-proj + LN  (f32_23 overlays S2,S3 — dead after the attn above)
    TW(11); gemm(S[5], nullptr, f32_23, nullptr, 8192, 1024);
    ln_kernel<<<8192, 256, 0, stream>>>(f32_23, (const float*)d_in[24], (const float*)d_in[25], nullptr, S[1]);   // tLN -> S1
    TW(15); gemm(S[0], nullptr, f32_23, nullptr, 12288, 1024);
    ln_kernel<<<12288, 256, 0, stream>>>(f32_23, (const float*)d_in[26], (const float*)d_in[27], nullptr, S[4]);  // iLN -> S4
    // text self-attn branch (length 64, image_mask)
    TW(16); gemm(S[1], nullptr, nullptr, S[0], 8192, 1024);             // tsQ -> S0
    TW(17); gemm(S[1], nullptr, nullptr, S[2], 8192, 1024);             // tsK -> S2
    TW(18); gemm(S[1], nullptr, nullptr, S[3], 8192, 1024);             // tsV -> S3
    attn_kernel<64, 64><<<512, 256, 0, stream>>>(S[0], S[2], S[3], iMask, iMask, S[5]);  // tsO -> S5
    TW(19); gemm(S[5], nullptr, f32_01, nullptr, 8192, 1024);           // f32_01 (S0,S1 dead)
    ln_kernel<<<8192, 256, 0, stream>>>(f32_01, (const float*)d_in[28], (const float*)d_in[29], (float*)d_out, nullptr);
    // image self-attn branch (length 96, text_mask)
    TW(20); gemm(S[4], nullptr, nullptr, S[2], 12288, 1024);            // isQ -> S2
    TW(21); gemm(S[4], nullptr, nullptr, S[3], 12288, 1024);            // isK -> S3
    TW(22); gemm(S[4], nullptr, nullptr, S[5], 12288, 1024);            // isV -> S5
    attn_kernel<96, 96><<<512, 256, 0, stream>>>(S[2], S[3], S[5], tMask, tMask, S[0]);  // isO -> S0
    TW(23); gemm(S[0], nullptr, f32_23, nullptr, 12288, 1024);          // f32_23 (S2,S3 dead)
    ln_kernel<<<12288, 256, 0, stream>>>(f32_23, (const float*)d_in[30], (const float*)d_in[31],
                                         (float*)d_out + 8388608, nullptr);
}

// Round 5
// 1075.774 us; speedup vs baseline: 1.1004x; 1.1004x over previous
//
#include <hip/hip_runtime.h>

typedef __bf16 bf16_t;
typedef __attribute__((ext_vector_type(8))) __bf16 bf16x8;
typedef __attribute__((ext_vector_type(4))) __bf16 bf16x4;
typedef __attribute__((ext_vector_type(4))) float f32x4;

// ---------------------------------------------------------------- helpers
__device__ __forceinline__ void async_copy16(const bf16_t* g, bf16_t* l) {
    __builtin_amdgcn_global_load_lds(
        (const __attribute__((address_space(1))) void*)g,
        (__attribute__((address_space(3))) void*)l, 16, 0, 0);
}

// ---------------------------------------------------------------- grouped W [K,1024] f32 -> Wt [parts*1024, K] bf16
__global__ __launch_bounds__(256) void transpose_group(const float* __restrict__ s0,
                                                       const float* __restrict__ s1,
                                                       const float* __restrict__ s2,
                                                       bf16_t* __restrict__ dst, int K) {
    // wave-uniform if/else select (no runtime-indexed pointer array -> no scratch spill)
    const float* in;
    if (blockIdx.z == 0) in = s0;
    else if (blockIdx.z == 1) in = s1;
    else in = s2;
    bf16_t* out = dst + (size_t)blockIdx.z * 1024 * K;
    __shared__ float tile[32][33];
    int t = threadIdx.x;
    int tx = t & 31, ty = t >> 5;              // 32 x 8
    int n0 = blockIdx.x * 32, k0 = blockIdx.y * 32;
#pragma unroll
    for (int i = 0; i < 4; i++) {
        int k = k0 + ty + i * 8;
        tile[ty + i * 8][tx] = in[(size_t)k * 1024 + n0 + tx];
    }
    __syncthreads();
#pragma unroll
    for (int i = 0; i < 4; i++) {
        int n = n0 + ty + i * 8;
        out[(size_t)n * K + k0 + tx] = (bf16_t)tile[tx][ty + i * 8];
    }
}

// fused bias: out[0..1023] = src, out[1024..2047] = 0
__global__ __launch_bounds__(256) void fuse_bias(const float* __restrict__ src,
                                                 float* __restrict__ out) {
    int i = blockIdx.x * 256 + threadIdx.x;
    out[i] = (i < 1024) ? src[i] : 0.f;
}

// ---------------------------------------------------------------- GEMM: [M,N] = A[M,K](bf16) @ Bt[N,K]^T (+bias)
// Split outputs: column segment c/1024 -> o{0,1,2}, each with row stride 1024 (bf16).
__global__ __launch_bounds__(256) void gemm_bt(const bf16_t* __restrict__ A,
                                               const bf16_t* __restrict__ Bt,
                                               const float* __restrict__ bias,
                                               bf16_t* __restrict__ o0,
                                               bf16_t* __restrict__ o1,
                                               bf16_t* __restrict__ o2,
                                               int M, int N, int K) {
    __shared__ bf16_t As[128 * 32];
    __shared__ bf16_t Bs[128 * 32];
    const int t = threadIdx.x;
    const int w = t >> 6, lane = t & 63;
    const int quad = lane >> 4, l16 = lane & 15;
    const int bm = blockIdx.x * 128, bn = blockIdx.y * 128;
    const int wm = (w >> 1) * 64, wn = (w & 1) * 64;

    const f32x4 zero = {0.f, 0.f, 0.f, 0.f};
    f32x4 acc[4][4];
#pragma unroll
    for (int i = 0; i < 4; i++)
#pragma unroll
        for (int j = 0; j < 4; j++) acc[i][j] = zero;

    const int srow = t >> 2;          // 0..63
    const int scol = (t & 3) * 8;
    const bf16_t* ga = A + (size_t)(bm + srow) * K + scol;
    const bf16_t* gb = Bt + (size_t)(bn + srow) * K + scol;
    bf16_t* la = As + w * 512;        // wave-uniform LDS base
    bf16_t* lb = Bs + w * 512;

    for (int k0 = 0; k0 < K; k0 += 32) {
        async_copy16(ga + k0, la);
        async_copy16(ga + k0 + (size_t)64 * K, la + 2048);
        async_copy16(gb + k0, lb);
        async_copy16(gb + k0 + (size_t)64 * K, lb + 2048);
        __syncthreads();
        bf16x8 af[4], bf[4];
#pragma unroll
        for (int i = 0; i < 4; i++)
            af[i] = *(const bf16x8*)(As + (wm + i * 16 + l16) * 32 + quad * 8);
#pragma unroll
        for (int j = 0; j < 4; j++)
            bf[j] = *(const bf16x8*)(Bs + (wn + j * 16 + l16) * 32 + quad * 8);
#pragma unroll
        for (int i = 0; i < 4; i++)
#pragma unroll
            for (int j = 0; j < 4; j++)
                acc[i][j] = __builtin_amdgcn_mfma_f32_16x16x32_bf16(af[i], bf[j], acc[i][j], 0, 0, 0);
        __syncthreads();
    }

    // wave-uniform output select (bn is uniform per block)
    bf16_t* out;
    if (bn < 1024) out = o0;
    else if (bn < 2048) out = o1;
    else out = o2;
    const int cb = bn & 1023;
    const int bbase = bn - cb;
#pragma unroll
    for (int i = 0; i < 4; i++) {
        int r0 = bm + wm + i * 16 + quad * 4;
#pragma unroll
        for (int j = 0; j < 4; j++) {
            int c = cb + wn + j * 16 + l16;
            float bsv = bias ? bias[bbase + c] : 0.f;
#pragma unroll
            for (int r = 0; r < 4; r++)
                out[(size_t)(r0 + r) * 1024 + c] = (bf16_t)(acc[i][j][r] + bsv);
        }
    }
}

// ---------------------------------------------------------------- GEMM with f32 A (fused convert; coalesced + conflict-free)
__global__ __launch_bounds__(256) void gemm_f32a(const float* __restrict__ A,
                                                 const bf16_t* __restrict__ Bt,
                                                 const float* __restrict__ bias,
                                                 bf16_t* __restrict__ o0,
                                                 bf16_t* __restrict__ o1,
                                                 int M, int N, int K) {
    constexpr int ASTR = 40;          // padded: write banks r*20%32 all distinct -> conflict-free
    __shared__ bf16_t As[128 * ASTR];
    __shared__ bf16_t Bs[128 * 32];
    const int t = threadIdx.x;
    const int w = t >> 6, lane = t & 63;
    const int quad = lane >> 4, l16 = lane & 15;
    const int bm = blockIdx.x * 128, bn = blockIdx.y * 128;
    const int wm = (w >> 1) * 64, wn = (w & 1) * 64;

    const f32x4 zero = {0.f, 0.f, 0.f, 0.f};
    f32x4 acc[4][4];
#pragma unroll
    for (int i = 0; i < 4; i++)
#pragma unroll
        for (int j = 0; j < 4; j++) acc[i][j] = zero;

    // A: 8 lanes/row x float4 -> 128B contiguous per row segment
    const int arow = t >> 3, ac4 = (t & 7) * 4;
    const float* ga = A + (size_t)(bm + arow) * K + ac4;
    const int srow = t >> 2, scol = (t & 3) * 8;
    const bf16_t* gb = Bt + (size_t)(bn + srow) * K + scol;
    bf16_t* lb = Bs + w * 512;

    for (int k0 = 0; k0 < K; k0 += 32) {
        async_copy16(gb + k0, lb);
        async_copy16(gb + k0 + (size_t)64 * K, lb + 2048);
        float4 av[4];
#pragma unroll
        for (int i = 0; i < 4; i++)
            av[i] = *(const float4*)(ga + (size_t)i * 32 * K + k0);
#pragma unroll
        for (int i = 0; i < 4; i++) {
            bf16x4 c;
            c[0] = (__bf16)av[i].x; c[1] = (__bf16)av[i].y;
            c[2] = (__bf16)av[i].z; c[3] = (__bf16)av[i].w;
            *(bf16x4*)(As + (arow + i * 32) * ASTR + ac4) = c;
        }
        __syncthreads();
        bf16x8 af[4], bf[4];
#pragma unroll
        for (int i = 0; i < 4; i++)
            af[i] = *(const bf16x8*)(As + (wm + i * 16 + l16) * ASTR + quad * 8);
#pragma unroll
        for (int j = 0; j < 4; j++)
            bf[j] = *(const bf16x8*)(Bs + (wn + j * 16 + l16) * 32 + quad * 8);
#pragma unroll
        for (int i = 0; i < 4; i++)
#pragma unroll
            for (int j = 0; j < 4; j++)
                acc[i][j] = __builtin_amdgcn_mfma_f32_16x16x32_bf16(af[i], bf[j], acc[i][j], 0, 0, 0);
        __syncthreads();
    }

    bf16_t* out = (bn < 1024) ? o0 : o1;
    const int cb = bn & 1023;
    const int bbase = bn - cb;
#pragma unroll
    for (int i = 0; i < 4; i++) {
        int r0 = bm + wm + i * 16 + quad * 4;
#pragma unroll
        for (int j = 0; j < 4; j++) {
            int c = cb + wn + j * 16 + l16;
            float bsv = bias ? bias[bbase + c] : 0.f;
#pragma unroll
            for (int r = 0; r < 4; r++)
                out[(size_t)(r0 + r) * 1024 + c] = (bf16_t)(acc[i][j][r] + bsv);
        }
    }
}

// ---------------------------------------------------------------- fused attention per (b, head) — unchanged (verified R2)
template <int LQ, int LK>
__global__ __launch_bounds__(256) void attn_kernel(const bf16_t* __restrict__ Q,
                                                   const bf16_t* __restrict__ Kb,
                                                   const bf16_t* __restrict__ V,
                                                   const int* __restrict__ qmask,
                                                   const int* __restrict__ kmask,
                                                   bf16_t* __restrict__ O) {
    constexpr int VSTR = LK + 8;
    constexpr int NQT = LQ / 16, NKT = LK / 16, NKB = LK / 32;
    __shared__ bf16_t Vt[256 * VSTR];
    __shared__ bf16_t Pb[4 * 16 * LK];

    const int t = threadIdx.x;
    const int w = t >> 6, lane = t & 63;
    const int quad = lane >> 4, l16 = lane & 15;
    const int b = blockIdx.x >> 2;
    const int h = blockIdx.x & 3;
    const int hoff = h * 256;

    for (int idx = t; idx < LK * 32; idx += 256) {
        int k = idx % LK;
        int e0 = (idx / LK) * 8;
        bf16x8 v = *(const bf16x8*)(V + (size_t)(b * LK + k) * 1024 + hoff + e0);
#pragma unroll
        for (int j = 0; j < 8; j++) Vt[(e0 + j) * VSTR + k] = v[j];
    }
    __syncthreads();

    bf16_t* P = Pb + w * (16 * LK);

    for (int qt = w; qt < NQT; qt += 4) {
        const int qrow = b * LQ + qt * 16;
        bf16x8 qf[8];
#pragma unroll
        for (int kb = 0; kb < 8; kb++)
            qf[kb] = *(const bf16x8*)(Q + (size_t)(qrow + l16) * 1024 + hoff + kb * 32 + quad * 8);

        f32x4 s[NKT];
        const f32x4 zero = {0.f, 0.f, 0.f, 0.f};
#pragma unroll
        for (int nt = 0; nt < NKT; nt++) {
            f32x4 a = zero;
#pragma unroll
            for (int kb = 0; kb < 8; kb++) {
                bf16x8 kf = *(const bf16x8*)(Kb + (size_t)(b * LK + nt * 16 + l16) * 1024 + hoff + kb * 32 + quad * 8);
                a = __builtin_amdgcn_mfma_f32_16x16x32_bf16(qf[kb], kf, a, 0, 0, 0);
            }
            s[nt] = a;
        }

        int km[NKT];
#pragma unroll
        for (int nt = 0; nt < NKT; nt++) km[nt] = kmask[b * LK + nt * 16 + l16];
        int qmv[4];
#pragma unroll
        for (int r = 0; r < 4; r++) qmv[r] = qmask[b * LQ + qt * 16 + quad * 4 + r];

        float rmax[4], rsum[4];
#pragma unroll
        for (int r = 0; r < 4; r++) rmax[r] = -3.0e38f;
#pragma unroll
        for (int nt = 0; nt < NKT; nt++)
#pragma unroll
            for (int r = 0; r < 4; r++) {
                float v = s[nt][r] * 0.0625f;
                bool ok = (qmv[r] != 0) && (km[nt] != 0);
                s[nt][r] = ok ? v : -3.0e38f;
                rmax[r] = fmaxf(rmax[r], s[nt][r]);
            }
#pragma unroll
        for (int r = 0; r < 4; r++)
            for (int off = 1; off < 16; off <<= 1)
                rmax[r] = fmaxf(rmax[r], __shfl_xor(rmax[r], off, 16));
#pragma unroll
        for (int r = 0; r < 4; r++) rsum[r] = 0.f;
#pragma unroll
        for (int nt = 0; nt < NKT; nt++)
#pragma unroll
            for (int r = 0; r < 4; r++) {
                float p = (s[nt][r] > -1.0e38f) ? __expf(s[nt][r] - rmax[r]) : 0.f;
                s[nt][r] = p;
                rsum[r] += p;
            }
#pragma unroll
        for (int r = 0; r < 4; r++)
            for (int off = 1; off < 16; off <<= 1)
                rsum[r] += __shfl_xor(rsum[r], off, 16);
#pragma unroll
        for (int r = 0; r < 4; r++) rsum[r] = (rsum[r] > 0.f) ? 1.f / rsum[r] : 0.f;

#pragma unroll
        for (int nt = 0; nt < NKT; nt++)
#pragma unroll
            for (int r = 0; r < 4; r++)
                P[(quad * 4 + r) * LK + nt * 16 + l16] = (bf16_t)(s[nt][r] * rsum[r]);
        asm volatile("s_waitcnt lgkmcnt(0)" ::: "memory");

        bf16x8 pf[NKB];
#pragma unroll
        for (int kb = 0; kb < NKB; kb++)
            pf[kb] = *(const bf16x8*)(P + l16 * LK + kb * 32 + quad * 8);

#pragma unroll
        for (int et = 0; et < 16; et++) {
            f32x4 o = zero;
#pragma unroll
            for (int kb = 0; kb < NKB; kb++) {
                bf16x8 vf = *(const bf16x8*)(Vt + (et * 16 + l16) * VSTR + kb * 32 + quad * 8);
                o = __builtin_amdgcn_mfma_f32_16x16x32_bf16(pf[kb], vf, o, 0, 0, 0);
            }
#pragma unroll
            for (int r = 0; r < 4; r++)
                O[(size_t)(qrow + quad * 4 + r) * 1024 + hoff + et * 16 + l16] = (bf16_t)o[r];
        }
    }
}

// ---------------------------------------------------------------- LayerNorm over D=1024, eps=1e-3 (bf16 input)
__global__ __launch_bounds__(256) void ln_kernel(const bf16_t* __restrict__ in,
                                                 const float* __restrict__ g,
                                                 const float* __restrict__ be,
                                                 float* __restrict__ outF,
                                                 bf16_t* __restrict__ outB) {
    __shared__ float red[8];
    const int row = blockIdx.x, t = threadIdx.x;
    bf16x4 xb = *(const bf16x4*)(in + (size_t)row * 1024 + t * 4);
    float x0 = (float)xb[0], x1 = (float)xb[1], x2 = (float)xb[2], x3 = (float)xb[3];
    float s = x0 + x1 + x2 + x3;
    float ss = x0 * x0 + x1 * x1 + x2 * x2 + x3 * x3;
    for (int off = 1; off < 64; off <<= 1) {
        s += __shfl_xor(s, off);
        ss += __shfl_xor(ss, off);
    }
    int w = t >> 6, lane = t & 63;
    if (lane == 0) { red[w * 2] = s; red[w * 2 + 1] = ss; }
    __syncthreads();
    if (t == 0) {
        float a = 0.f, b2 = 0.f;
        for (int i = 0; i < 4; i++) { a += red[i * 2]; b2 += red[i * 2 + 1]; }
        red[0] = a; red[1] = b2;
    }
    __syncthreads();
    float mean = red[0] * (1.f / 1024.f);
    float var = red[1] * (1.f / 1024.f) - mean * mean;
    float rstd = rsqrtf(var + 1e-3f);
    float4 gv = *(const float4*)(g + t * 4);
    float4 bv = *(const float4*)(be + t * 4);
    float y0 = (x0 - mean) * rstd * gv.x + bv.x;
    float y1 = (x1 - mean) * rstd * gv.y + bv.y;
    float y2 = (x2 - mean) * rstd * gv.z + bv.z;
    float y3 = (x3 - mean) * rstd * gv.w + bv.w;
    if (outF) {
        float4 o = {y0, y1, y2, y3};
        *(float4*)(outF + (size_t)row * 1024 + t * 4) = o;
    }
    if (outB) {
        bf16x4 o;
        o[0] = (__bf16)y0; o[1] = (__bf16)y1; o[2] = (__bf16)y2; o[3] = (__bf16)y3;
        *(bf16x4*)(outB + (size_t)row * 1024 + t * 4) = o;
    }
}

// ---------------------------------------------------------------- host orchestration
// Workspace plan — total 145 MB (R2's 148 MB proven safe):
//   WB   [0,8MB)      : one rotating transposed-weight buffer (max fused group 8 MB)
//   bias [8MB,9MB)    : two fused 2048-f32 bias vectors
//   arena [9MB,145MB) : MB offsets below, liveness audited per step in comments
extern "C" void kernel_launch(void* const* d_in, const int* in_sizes, int n_in,
                              void* d_out, int out_size, void* d_ws, size_t ws_size,
                              hipStream_t stream) {
    (void)in_sizes; (void)n_in; (void)out_size; (void)ws_size;
    const float* tE = (const float*)d_in[0];   // [128*96,1024]
    const float* iE = (const float*)d_in[1];   // [128*64,2048]
    const int* tMask = (const int*)d_in[2];
    const int* iMask = (const int*)d_in[3];

    const size_t MB = 1048576;
    char* ws = (char*)d_ws;
    bf16_t* WB = (bf16_t*)ws;
    float* biasT = (float*)(ws + 8 * MB);
    float* biasI = biasT + 2048;
    char* AB = ws + 9 * MB;
    auto buf = [&](int mb) { return (bf16_t*)(AB + (size_t)mb * MB); };

    auto TG = [&](int i0, int i1, int i2, int parts, int K) {
        transpose_group<<<dim3(32, K / 32, parts), 256, 0, stream>>>(
            (const float*)d_in[i0], i1 >= 0 ? (const float*)d_in[i1] : (const float*)d_in[i0],
            i2 >= 0 ? (const float*)d_in[i2] : (const float*)d_in[i0], WB, K);
    };
    auto gemm = [&](const bf16_t* A, const float* bias, bf16_t* out0, bf16_t* out1,
                    bf16_t* out2, int M, int N, int K) {
        gemm_bt<<<dim3(M / 128, N / 128), 256, 0, stream>>>(A, WB, bias, out0, out1, out2, M, N, K);
    };

    fuse_bias<<<8, 256, 0, stream>>>((const float*)d_in[5], biasT);
    fuse_bias<<<8, 256, 0, stream>>>((const float*)d_in[7], biasI);

    // 1. [W_tp|ta_Wv] <- tE(f32):  tP -> 32, taV -> 64
    TG(4, 10, -1, 2, 1024);
    gemm_f32a<<<dim3(96, 16), 256, 0, stream>>>(tE, WB, biasT, buf(32), buf(64), 12288, 2048, 1024);
    // 2. [W_ip|ia_Wv] <- iE(f32):  iP -> 0, iaV -> 16
    TG(6, 14, -1, 2, 2048);
    gemm_f32a<<<dim3(64, 16), 256, 0, stream>>>(iE, WB, biasI, buf(0), buf(16), 8192, 2048, 2048);
    // 3. [ta_Wk|ia_Wq] <- tP(32):  taK -> 88, iaQ -> 112   (tP dead after)
    TG(9, 12, -1, 2, 1024);
    gemm(buf(32), nullptr, buf(88), buf(112), nullptr, 12288, 2048, 1024);
    // 4. [ta_Wq|ia_Wk] <- iP(0):   taQ -> 32, iaK -> 48    (iP dead after)
    TG(8, 13, -1, 2, 1024);
    gemm(buf(0), nullptr, buf(32), buf(48), nullptr, 8192, 2048, 1024);
    // 5. attn ta: Q=taQ(32) K=taK(88) V=taV(64) -> taO 0   (taQ,taK,taV dead after)
    attn_kernel<64, 96><<<512, 256, 0, stream>>>(buf(32), buf(88), buf(64), iMask, tMask, buf(0));
    // 6. attn ia: Q=iaQ(112) K=iaK(48) V=iaV(16) -> iaO 64
    attn_kernel<96, 64><<<512, 256, 0, stream>>>(buf(112), buf(48), buf(16), tMask, iMask, buf(64));
    // 7. ta_Wo <- taO(0) -> lnin 32; LN -> tLN 88
    TG(11, -1, -1, 1, 1024);
    gemm(buf(0), nullptr, buf(32), nullptr, nullptr, 8192, 1024, 1024);
    ln_kernel<<<8192, 256, 0, stream>>>(buf(32), (const float*)d_in[24], (const float*)d_in[25], nullptr, buf(88));
    // 8. ia_Wo <- iaO(64) -> lnin 0; LN -> iLN 104
    TG(15, -1, -1, 1, 1024);
    gemm(buf(64), nullptr, buf(0), nullptr, nullptr, 12288, 1024, 1024);
    ln_kernel<<<12288, 256, 0, stream>>>(buf(0), (const float*)d_in[26], (const float*)d_in[27], nullptr, buf(104));
    // 9. [ts_Wq|ts_Wk|ts_Wv] <- tLN(88): tsQ 0, tsK 16, tsV 32
    TG(16, 17, 18, 3, 1024);
    gemm(buf(88), nullptr, buf(0), buf(16), buf(32), 8192, 3072, 1024);
    // 10. attn ts -> tsO 48
    attn_kernel<64, 64><<<512, 256, 0, stream>>>(buf(0), buf(16), buf(32), iMask, iMask, buf(48));
    // 11. ts_Wo <- tsO(48) -> lnin 64; LN -> d_out (text, f32)
    TG(19, -1, -1, 1, 1024);
    gemm(buf(48), nullptr, buf(64), nullptr, nullptr, 8192, 1024, 1024);
    ln_kernel<<<8192, 256, 0, stream>>>(buf(64), (const float*)d_in[28], (const float*)d_in[29], (float*)d_out, nullptr);
    // 12. [is_Wq|is_Wk|is_Wv] <- iLN(104): isQ 0, isK 24, isV 48
    TG(20, 21, 22, 3, 1024);
    gemm(buf(104), nullptr, buf(0), buf(24), buf(48), 12288, 3072, 1024);
    // 13. attn is -> isO 72
    attn_kernel<96, 96><<<512, 256, 0, stream>>>(buf(0), buf(24), buf(48), tMask, tMask, buf(72));
    // 14. is_Wo <- isO(72) -> lnin 96; LN -> d_out+8M (image, f32)
    TG(23, -1, -1, 1, 1024);
    gemm(buf(72), nullptr, buf(96), nullptr, nullptr, 12288, 1024, 1024);
    ln_kernel<<<12288, 256, 0, stream>>>(buf(96), (const float*)d_in[30], (const float*)d_in[31],
                                         (float*)d_out + 8388608, nullptr);
}

// Round 6
// 1072.026 us; speedup vs baseline: 1.1043x; 1.0035x over previous
//
#include <hip/hip_runtime.h>

typedef __bf16 bf16_t;
typedef __attribute__((ext_vector_type(8))) __bf16 bf16x8;
typedef __attribute__((ext_vector_type(4))) __bf16 bf16x4;
typedef __attribute__((ext_vector_type(4))) float f32x4;

// ---------------------------------------------------------------- helpers
__device__ __forceinline__ void async_copy16(const bf16_t* g, bf16_t* l) {
    __builtin_amdgcn_global_load_lds(
        (const __attribute__((address_space(1))) void*)g,
        (__attribute__((address_space(3))) void*)l, 16, 0, 0);
}

// ---------------------------------------------------------------- f32 -> bf16 elementwise (4 elems/thread)
__global__ __launch_bounds__(256) void cvt_bf16(const float* __restrict__ in,
                                                bf16_t* __restrict__ out) {
    int i = (blockIdx.x * 256 + threadIdx.x) * 4;
    float4 v = *(const float4*)(in + i);
    bf16x4 o;
    o[0] = (__bf16)v.x; o[1] = (__bf16)v.y; o[2] = (__bf16)v.z; o[3] = (__bf16)v.w;
    *(bf16x4*)(out + i) = o;
}

// ---------------------------------------------------------------- grouped W [K,1024] f32 -> Wt [parts*1024, K] bf16
__global__ __launch_bounds__(256) void transpose_group(const float* __restrict__ s0,
                                                       const float* __restrict__ s1,
                                                       const float* __restrict__ s2,
                                                       bf16_t* __restrict__ dst, int K) {
    // wave-uniform if/else select (runtime-indexed pointer arrays killed containers in R3/R4)
    const float* in;
    if (blockIdx.z == 0) in = s0;
    else if (blockIdx.z == 1) in = s1;
    else in = s2;
    bf16_t* out = dst + (size_t)blockIdx.z * 1024 * K;
    __shared__ float tile[32][33];
    int t = threadIdx.x;
    int tx = t & 31, ty = t >> 5;              // 32 x 8
    int n0 = blockIdx.x * 32, k0 = blockIdx.y * 32;
#pragma unroll
    for (int i = 0; i < 4; i++) {
        int k = k0 + ty + i * 8;
        tile[ty + i * 8][tx] = in[(size_t)k * 1024 + n0 + tx];
    }
    __syncthreads();
#pragma unroll
    for (int i = 0; i < 4; i++) {
        int n = n0 + ty + i * 8;
        out[(size_t)n * K + k0 + tx] = (bf16_t)tile[tx][ty + i * 8];
    }
}

// fused bias: out[0..1023] = src, out[1024..2047] = 0
__global__ __launch_bounds__(256) void fuse_bias(const float* __restrict__ src,
                                                 float* __restrict__ out) {
    int i = blockIdx.x * 256 + threadIdx.x;
    out[i] = (i < 1024) ? src[i] : 0.f;
}

// ---------------------------------------------------------------- GEMM: [M,N] = A[M,K](bf16) @ Bt[N,K]^T (+bias)
// Split outputs: column segment c/1024 -> o{0,1,2}, each with row stride 1024 (bf16).
__global__ __launch_bounds__(256) void gemm_bt(const bf16_t* __restrict__ A,
                                               const bf16_t* __restrict__ Bt,
                                               const float* __restrict__ bias,
                                               bf16_t* __restrict__ o0,
                                               bf16_t* __restrict__ o1,
                                               bf16_t* __restrict__ o2,
                                               int M, int N, int K) {
    __shared__ bf16_t As[128 * 32];
    __shared__ bf16_t Bs[128 * 32];
    const int t = threadIdx.x;
    const int w = t >> 6, lane = t & 63;
    const int quad = lane >> 4, l16 = lane & 15;
    const int bm = blockIdx.x * 128, bn = blockIdx.y * 128;
    const int wm = (w >> 1) * 64, wn = (w & 1) * 64;

    const f32x4 zero = {0.f, 0.f, 0.f, 0.f};
    f32x4 acc[4][4];
#pragma unroll
    for (int i = 0; i < 4; i++)
#pragma unroll
        for (int j = 0; j < 4; j++) acc[i][j] = zero;

    const int srow = t >> 2;          // 0..63
    const int scol = (t & 3) * 8;
    const bf16_t* ga = A + (size_t)(bm + srow) * K + scol;
    const bf16_t* gb = Bt + (size_t)(bn + srow) * K + scol;
    bf16_t* la = As + w * 512;        // wave-uniform LDS base
    bf16_t* lb = Bs + w * 512;

    for (int k0 = 0; k0 < K; k0 += 32) {
        async_copy16(ga + k0, la);
        async_copy16(ga + k0 + (size_t)64 * K, la + 2048);
        async_copy16(gb + k0, lb);
        async_copy16(gb + k0 + (size_t)64 * K, lb + 2048);
        __syncthreads();
        bf16x8 af[4], bf[4];
#pragma unroll
        for (int i = 0; i < 4; i++)
            af[i] = *(const bf16x8*)(As + (wm + i * 16 + l16) * 32 + quad * 8);
#pragma unroll
        for (int j = 0; j < 4; j++)
            bf[j] = *(const bf16x8*)(Bs + (wn + j * 16 + l16) * 32 + quad * 8);
#pragma unroll
        for (int i = 0; i < 4; i++)
#pragma unroll
            for (int j = 0; j < 4; j++)
                acc[i][j] = __builtin_amdgcn_mfma_f32_16x16x32_bf16(af[i], bf[j], acc[i][j], 0, 0, 0);
        __syncthreads();
    }

    // wave-uniform output select (bn is uniform per block)
    bf16_t* out;
    if (bn < 1024) out = o0;
    else if (bn < 2048) out = o1;
    else out = o2;
    const int cb = bn & 1023;
    const int bbase = bn - cb;
#pragma unroll
    for (int i = 0; i < 4; i++) {
        int r0 = bm + wm + i * 16 + quad * 4;
#pragma unroll
        for (int j = 0; j < 4; j++) {
            int c = cb + wn + j * 16 + l16;
            float bsv = bias ? bias[bbase + c] : 0.f;
#pragma unroll
            for (int r = 0; r < 4; r++)
                out[(size_t)(r0 + r) * 1024 + c] = (bf16_t)(acc[i][j][r] + bsv);
        }
    }
}

// ---------------------------------------------------------------- fused attention per (b, head) — unchanged (verified R2/R5)
template <int LQ, int LK>
__global__ __launch_bounds__(256) void attn_kernel(const bf16_t* __restrict__ Q,
                                                   const bf16_t* __restrict__ Kb,
                                                   const bf16_t* __restrict__ V,
                                                   const int* __restrict__ qmask,
                                                   const int* __restrict__ kmask,
                                                   bf16_t* __restrict__ O) {
    constexpr int VSTR = LK + 8;
    constexpr int NQT = LQ / 16, NKT = LK / 16, NKB = LK / 32;
    __shared__ bf16_t Vt[256 * VSTR];
    __shared__ bf16_t Pb[4 * 16 * LK];

    const int t = threadIdx.x;
    const int w = t >> 6, lane = t & 63;
    const int quad = lane >> 4, l16 = lane & 15;
    const int b = blockIdx.x >> 2;
    const int h = blockIdx.x & 3;
    const int hoff = h * 256;

    for (int idx = t; idx < LK * 32; idx += 256) {
        int k = idx % LK;
        int e0 = (idx / LK) * 8;
        bf16x8 v = *(const bf16x8*)(V + (size_t)(b * LK + k) * 1024 + hoff + e0);
#pragma unroll
        for (int j = 0; j < 8; j++) Vt[(e0 + j) * VSTR + k] = v[j];
    }
    __syncthreads();

    bf16_t* P = Pb + w * (16 * LK);

    for (int qt = w; qt < NQT; qt += 4) {
        const int qrow = b * LQ + qt * 16;
        bf16x8 qf[8];
#pragma unroll
        for (int kb = 0; kb < 8; kb++)
            qf[kb] = *(const bf16x8*)(Q + (size_t)(qrow + l16) * 1024 + hoff + kb * 32 + quad * 8);

        f32x4 s[NKT];
        const f32x4 zero = {0.f, 0.f, 0.f, 0.f};
#pragma unroll
        for (int nt = 0; nt < NKT; nt++) {
            f32x4 a = zero;
#pragma unroll
            for (int kb = 0; kb < 8; kb++) {
                bf16x8 kf = *(const bf16x8*)(Kb + (size_t)(b * LK + nt * 16 + l16) * 1024 + hoff + kb * 32 + quad * 8);
                a = __builtin_amdgcn_mfma_f32_16x16x32_bf16(qf[kb], kf, a, 0, 0, 0);
            }
            s[nt] = a;
        }

        int km[NKT];
#pragma unroll
        for (int nt = 0; nt < NKT; nt++) km[nt] = kmask[b * LK + nt * 16 + l16];
        int qmv[4];
#pragma unroll
        for (int r = 0; r < 4; r++) qmv[r] = qmask[b * LQ + qt * 16 + quad * 4 + r];

        float rmax[4], rsum[4];
#pragma unroll
        for (int r = 0; r < 4; r++) rmax[r] = -3.0e38f;
#pragma unroll
        for (int nt = 0; nt < NKT; nt++)
#pragma unroll
            for (int r = 0; r < 4; r++) {
                float v = s[nt][r] * 0.0625f;
                bool ok = (qmv[r] != 0) && (km[nt] != 0);
                s[nt][r] = ok ? v : -3.0e38f;
                rmax[r] = fmaxf(rmax[r], s[nt][r]);
            }
#pragma unroll
        for (int r = 0; r < 4; r++)
            for (int off = 1; off < 16; off <<= 1)
                rmax[r] = fmaxf(rmax[r], __shfl_xor(rmax[r], off, 16));
#pragma unroll
        for (int r = 0; r < 4; r++) rsum[r] = 0.f;
#pragma unroll
        for (int nt = 0; nt < NKT; nt++)
#pragma unroll
            for (int r = 0; r < 4; r++) {
                float p = (s[nt][r] > -1.0e38f) ? __expf(s[nt][r] - rmax[r]) : 0.f;
                s[nt][r] = p;
                rsum[r] += p;
            }
#pragma unroll
        for (int r = 0; r < 4; r++)
            for (int off = 1; off < 16; off <<= 1)
                rsum[r] += __shfl_xor(rsum[r], off, 16);
#pragma unroll
        for (int r = 0; r < 4; r++) rsum[r] = (rsum[r] > 0.f) ? 1.f / rsum[r] : 0.f;

#pragma unroll
        for (int nt = 0; nt < NKT; nt++)
#pragma unroll
            for (int r = 0; r < 4; r++)
                P[(quad * 4 + r) * LK + nt * 16 + l16] = (bf16_t)(s[nt][r] * rsum[r]);
        asm volatile("s_waitcnt lgkmcnt(0)" ::: "memory");

        bf16x8 pf[NKB];
#pragma unroll
        for (int kb = 0; kb < NKB; kb++)
            pf[kb] = *(const bf16x8*)(P + l16 * LK + kb * 32 + quad * 8);

#pragma unroll
        for (int et = 0; et < 16; et++) {
            f32x4 o = zero;
#pragma unroll
            for (int kb = 0; kb < NKB; kb++) {
                bf16x8 vf = *(const bf16x8*)(Vt + (et * 16 + l16) * VSTR + kb * 32 + quad * 8);
                o = __builtin_amdgcn_mfma_f32_16x16x32_bf16(pf[kb], vf, o, 0, 0, 0);
            }
#pragma unroll
            for (int r = 0; r < 4; r++)
                O[(size_t)(qrow + quad * 4 + r) * 1024 + hoff + et * 16 + l16] = (bf16_t)o[r];
        }
    }
}

// ---------------------------------------------------------------- LayerNorm over D=1024, eps=1e-3 (bf16 input)
__global__ __launch_bounds__(256) void ln_kernel(const bf16_t* __restrict__ in,
                                                 const float* __restrict__ g,
                                                 const float* __restrict__ be,
                                                 float* __restrict__ outF,
                                                 bf16_t* __restrict__ outB) {
    __shared__ float red[8];
    const int row = blockIdx.x, t = threadIdx.x;
    bf16x4 xb = *(const bf16x4*)(in + (size_t)row * 1024 + t * 4);
    float x0 = (float)xb[0], x1 = (float)xb[1], x2 = (float)xb[2], x3 = (float)xb[3];
    float s = x0 + x1 + x2 + x3;
    float ss = x0 * x0 + x1 * x1 + x2 * x2 + x3 * x3;
    for (int off = 1; off < 64; off <<= 1) {
        s += __shfl_xor(s, off);
        ss += __shfl_xor(ss, off);
    }
    int w = t >> 6, lane = t & 63;
    if (lane == 0) { red[w * 2] = s; red[w * 2 + 1] = ss; }
    __syncthreads();
    if (t == 0) {
        float a = 0.f, b2 = 0.f;
        for (int i = 0; i < 4; i++) { a += red[i * 2]; b2 += red[i * 2 + 1]; }
        red[0] = a; red[1] = b2;
    }
    __syncthreads();
    float mean = red[0] * (1.f / 1024.f);
    float var = red[1] * (1.f / 1024.f) - mean * mean;
    float rstd = rsqrtf(var + 1e-3f);
    float4 gv = *(const float4*)(g + t * 4);
    float4 bv = *(const float4*)(be + t * 4);
    float y0 = (x0 - mean) * rstd * gv.x + bv.x;
    float y1 = (x1 - mean) * rstd * gv.y + bv.y;
    float y2 = (x2 - mean) * rstd * gv.z + bv.z;
    float y3 = (x3 - mean) * rstd * gv.w + bv.w;
    if (outF) {
        float4 o = {y0, y1, y2, y3};
        *(float4*)(outF + (size_t)row * 1024 + t * 4) = o;
    }
    if (outB) {
        bf16x4 o;
        o[0] = (__bf16)y0; o[1] = (__bf16)y1; o[2] = (__bf16)y2; o[3] = (__bf16)y3;
        *(bf16x4*)(outB + (size_t)row * 1024 + t * 4) = o;
    }
}

// ---------------------------------------------------------------- host orchestration
// Workspace plan — total 145 MB (unchanged from R5, proven safe):
//   WB   [0,8MB)      : one rotating transposed-weight buffer (max fused group 8 MB)
//   bias [8MB,9MB)    : two fused 2048-f32 bias vectors
//   arena [9MB,145MB) : MB offsets below, liveness audited per step in comments
// New vs R5: tE/iE pre-converted to bf16 (TB/IB transient at buf(88), dead before
// step 3 claims that region), gemm_f32a eliminated.
extern "C" void kernel_launch(void* const* d_in, const int* in_sizes, int n_in,
                              void* d_out, int out_size, void* d_ws, size_t ws_size,
                              hipStream_t stream) {
    (void)in_sizes; (void)n_in; (void)out_size; (void)ws_size;
    const float* tE = (const float*)d_in[0];   // [128*96,1024]
    const float* iE = (const float*)d_in[1];   // [128*64,2048]
    const int* tMask = (const int*)d_in[2];
    const int* iMask = (const int*)d_in[3];

    const size_t MB = 1048576;
    char* ws = (char*)d_ws;
    bf16_t* WB = (bf16_t*)ws;
    float* biasT = (float*)(ws + 8 * MB);
    float* biasI = biasT + 2048;
    char* AB = ws + 9 * MB;
    auto buf = [&](int mb) { return (bf16_t*)(AB + (size_t)mb * MB); };

    auto TG = [&](int i0, int i1, int i2, int parts, int K) {
        transpose_group<<<dim3(32, K / 32, parts), 256, 0, stream>>>(
            (const float*)d_in[i0], i1 >= 0 ? (const float*)d_in[i1] : (const float*)d_in[i0],
            i2 >= 0 ? (const float*)d_in[i2] : (const float*)d_in[i0], WB, K);
    };
    auto gemm = [&](const bf16_t* A, const float* bias, bf16_t* out0, bf16_t* out1,
                    bf16_t* out2, int M, int N, int K) {
        gemm_bt<<<dim3(M / 128, N / 128), 256, 0, stream>>>(A, WB, bias, out0, out1, out2, M, N, K);
    };

    fuse_bias<<<8, 256, 0, stream>>>((const float*)d_in[5], biasT);
    fuse_bias<<<8, 256, 0, stream>>>((const float*)d_in[7], biasI);

    // 1. TB = bf16(tE) @ buf(88) [88,112); [W_tp|ta_Wv]: tP -> 32, taV -> 64. TB dead after.
    cvt_bf16<<<12288, 256, 0, stream>>>(tE, buf(88));
    TG(4, 10, -1, 2, 1024);
    gemm(buf(88), biasT, buf(32), buf(64), nullptr, 12288, 2048, 1024);
    // 2. IB = bf16(iE) @ buf(88) [88,120); [W_ip|ia_Wv]: iP -> 0, iaV -> 16. IB dead after.
    cvt_bf16<<<16384, 256, 0, stream>>>(iE, buf(88));
    TG(6, 14, -1, 2, 2048);
    gemm(buf(88), biasI, buf(0), buf(16), nullptr, 8192, 2048, 2048);
    // 3. [ta_Wk|ia_Wq] <- tP(32):  taK -> 88, iaQ -> 112   (tP dead after)
    TG(9, 12, -1, 2, 1024);
    gemm(buf(32), nullptr, buf(88), buf(112), nullptr, 12288, 2048, 1024);
    // 4. [ta_Wq|ia_Wk] <- iP(0):   taQ -> 32, iaK -> 48    (iP dead after)
    TG(8, 13, -1, 2, 1024);
    gemm(buf(0), nullptr, buf(32), buf(48), nullptr, 8192, 2048, 1024);
    // 5. attn ta: Q=taQ(32) K=taK(88) V=taV(64) -> taO 0   (taQ,taK,taV dead after)
    attn_kernel<64, 96><<<512, 256, 0, stream>>>(buf(32), buf(88), buf(64), iMask, tMask, buf(0));
    // 6. attn ia: Q=iaQ(112) K=iaK(48) V=iaV(16) -> iaO 64
    attn_kernel<96, 64><<<512, 256, 0, stream>>>(buf(112), buf(48), buf(16), tMask, iMask, buf(64));
    // 7. ta_Wo <- taO(0) -> lnin 32; LN -> tLN 88
    TG(11, -1, -1, 1, 1024);
    gemm(buf(0), nullptr, buf(32), nullptr, nullptr, 8192, 1024, 1024);
    ln_kernel<<<8192, 256, 0, stream>>>(buf(32), (const float*)d_in[24], (const float*)d_in[25], nullptr, buf(88));
    // 8. ia_Wo <- iaO(64) -> lnin 0; LN -> iLN 104
    TG(15, -1, -1, 1, 1024);
    gemm(buf(64), nullptr, buf(0), nullptr, nullptr, 12288, 1024, 1024);
    ln_kernel<<<12288, 256, 0, stream>>>(buf(0), (const float*)d_in[26], (const float*)d_in[27], nullptr, buf(104));
    // 9. [ts_Wq|ts_Wk|ts_Wv] <- tLN(88): tsQ 0, tsK 16, tsV 32
    TG(16, 17, 18, 3, 1024);
    gemm(buf(88), nullptr, buf(0), buf(16), buf(32), 8192, 3072, 1024);
    // 10. attn ts -> tsO 48
    attn_kernel<64, 64><<<512, 256, 0, stream>>>(buf(0), buf(16), buf(32), iMask, iMask, buf(48));
    // 11. ts_Wo <- tsO(48) -> lnin 64; LN -> d_out (text, f32)
    TG(19, -1, -1, 1, 1024);
    gemm(buf(48), nullptr, buf(64), nullptr, nullptr, 8192, 1024, 1024);
    ln_kernel<<<8192, 256, 0, stream>>>(buf(64), (const float*)d_in[28], (const float*)d_in[29], (float*)d_out, nullptr);
    // 12. [is_Wq|is_Wk|is_Wv] <- iLN(104): isQ 0, isK 24, isV 48
    TG(20, 21, 22, 3, 1024);
    gemm(buf(104), nullptr, buf(0), buf(24), buf(48), 12288, 3072, 1024);
    // 13. attn is -> isO 72
    attn_kernel<96, 96><<<512, 256, 0, stream>>>(buf(0), buf(24), buf(48), tMask, tMask, buf(72));
    // 14. is_Wo <- isO(72) -> lnin 96; LN -> d_out+8M (image, f32)
    TG(23, -1, -1, 1, 1024);
    gemm(buf(72), nullptr, buf(96), nullptr, nullptr, 12288, 1024, 1024);
    ln_kernel<<<12288, 256, 0, stream>>>(buf(96), (const float*)d_in[30], (const float*)d_in[31],
                                         (float*)d_out + 8388608, nullptr);
}